// Round 17
// baseline (2521.446 us; speedup 1.0000x reference)
//
#include <hip/hip_runtime.h>

// Soft-DTW, gamma=1.0, B=64, N=M=1024. Linear-weight cells + integer-exponent
// scale tracking (R15/R16 numerics, proven absmax 0.0).
// R17: 4 COLUMN PANELS per batch -> 256 blocks (all CUs). The cross-round
// invariant was the per-CU scattered-lane-request floor (~1.6 cyc/request,
// 1024 req/iter in R15/R16). Panels cut per-CU requests 4x (TPB=64, KC=4:
// 256 req/iter) and per-panel ITER to 319. Panels pipeline via a global
// per-quad mailbox (4 edge-W + S + flag) with device-scope release/acquire
// atomics (cross-XCD safe); flags cleared to -1 per launch by hipMemsetAsync.
// Consumer prefetches quad p+1 one iteration early (hides ~300cyc global rd).
// Intra-panel handoff: single wave, pipelined __shfl_up (proven skeleton).
// D: asm global_load_dwordx4 ring, 4 slots (16 outstanding), vmcnt(12).

#define LOG2E 1.4426950408889634f
#define LN2  0.6931471805599453f

constexpr int N = 1024;
constexpr int TPB = 64;              // one wave per block
constexpr int KC = 4;                // columns per thread
constexpr int RQ = 4;                // rows per iteration (quad)
constexpr int NQ = N / RQ;           // 256 quads
constexpr int NPAN = 4;              // column panels per batch
constexpr int PC = N / NPAN;         // 256 columns per panel
constexpr int ITER = 320;            // last real iteration: 255 + 63 = 318

__device__ __forceinline__ float fexp2(float x){float r;asm("v_exp_f32 %0, %1":"=v"(r):"v"(x));return r;}
__device__ __forceinline__ float flog2(float x){float r;asm("v_log_f32 %0, %1":"=v"(r):"v"(x));return r;}
__device__ __forceinline__ int   ffrexpe(float x){int r;asm("v_frexp_exp_i32_f32 %0, %1":"=v"(r):"v"(x));return r;}
__device__ __forceinline__ float fldexp(float x, int e){float r;asm("v_ldexp_f32 %0, %1, %2":"=v"(r):"v"(x),"v"(e));return r;}
__device__ __forceinline__ void gload4(float4& d, const float* p){
    asm volatile("global_load_dwordx4 %0, %1, off" : "=v"(d) : "v"(p));
}

__global__ __launch_bounds__(TPB, 1)
void softdtw_kernel(const float* __restrict__ D, float* __restrict__ out,
                    int* __restrict__ flg, float* __restrict__ payf){
    const int blk = blockIdx.x;
    const int b = blk >> 2;              // batch
    const int q = blk & 3;               // panel
    const int t = threadIdx.x;
    const float* __restrict__ bp = D + (size_t)b * N * N + q * PC + t * KC;

    const bool isProd = (t == TPB - 1) && (q < NPAN - 1);
    const bool isCons = (t == 0) && (q > 0);
    const int prodBase = (b * (NPAN - 1) + q) * NQ;        // boundary after panel q
    const int consBase = (b * (NPAN - 1) + (q - 1)) * NQ;  // boundary before panel q

    float pW[KC] = {0,0,0,0};            // row-above weights (my scale)
    int   S = 0;                          // scale: W_true = W * 2^S
    float luW = (t == 0 && q == 0) ? 1.0f : 0.0f;   // DP[0][0] corner
    float exW[RQ] = {0,0,0,0};
    int   exS = 0;
    float nW[RQ] = {0,0,0,0};
    int   nS = 0;
    float mpW[4] = {0,0,0,0};            // prefetched mailbox payload
    int   mpS = 0;

    float4 ld[4][RQ];                    // load ring: 4 slots
#pragma unroll
    for (int x = 0; x < 4; ++x) {
        int pc = min(max(x - t, 0), NQ - 1);
        const float* a = bp + (size_t)(pc * RQ) * N;
#pragma unroll
        for (int r = 0; r < RQ; ++r) gload4(ld[x][r], a + (size_t)r * N);
    }

    // prologue: consumer prefetches quad 0's mailbox
    if (isCons) {
        while (__hip_atomic_load(&flg[consBase], __ATOMIC_ACQUIRE, __HIP_MEMORY_SCOPE_AGENT) < 0) {}
        const float* pp = payf + (size_t)consBase * 5;
        mpW[0] = __hip_atomic_load(pp + 0, __ATOMIC_RELAXED, __HIP_MEMORY_SCOPE_AGENT);
        mpW[1] = __hip_atomic_load(pp + 1, __ATOMIC_RELAXED, __HIP_MEMORY_SCOPE_AGENT);
        mpW[2] = __hip_atomic_load(pp + 2, __ATOMIC_RELAXED, __HIP_MEMORY_SCOPE_AGENT);
        mpW[3] = __hip_atomic_load(pp + 3, __ATOMIC_RELAXED, __HIP_MEMORY_SCOPE_AGENT);
        mpS    = __hip_atomic_load((const int*)(pp + 4), __ATOMIC_RELAXED, __HIP_MEMORY_SCOPE_AGENT);
    }

    for (int jb = 0; jb < ITER; jb += 4) {
#pragma unroll
        for (int u = 0; u < 4; ++u) {
            const int p = jb + u - t;
            const bool active = (unsigned)p < (unsigned)NQ;

            // incoming left edges
            float i0 = nW[0], i1 = nW[1], i2 = nW[2], i3 = nW[3];
            int   iS = nS;
            if (isCons) { i0 = mpW[0]; i1 = mpW[1]; i2 = mpW[2]; i3 = mpW[3]; iS = mpS; }
            if (t == 0 && q == 0) { i0 = i1 = i2 = i3 = 0.0f; iS = S; }

            // anchor my scale at my first quad
            if (p == 0) S = (t == 0 && q == 0) ? 0 : iS;

            // oldest load slot landed: 16 outstanding -> 12
            asm volatile("s_waitcnt vmcnt(12)" ::: "memory");
            __builtin_amdgcn_sched_barrier(0);

            // off-chain per-cell factors f = 2^(-d*log2e)
            const int slot = u;
            float f[16];
#pragma unroll
            for (int r = 0; r < RQ; ++r) {
                const float4 dv = ld[slot][r];
                f[r*4+0] = fexp2(-LOG2E * dv.x);
                f[r*4+1] = fexp2(-LOG2E * dv.y);
                f[r*4+2] = fexp2(-LOG2E * dv.z);
                f[r*4+3] = fexp2(-LOG2E * dv.w);
            }

            // import edges into my scale (pure VALU)
            const int dS = iS - S;
            float eW[RQ];
            eW[0] = fldexp(i0, dS); eW[1] = fldexp(i1, dS);
            eW[2] = fldexp(i2, dS); eW[3] = fldexp(i3, dS);

            // ---- 16 cells: W = f*(up + diag + left) ----
            float a0 = pW[0], a1 = pW[1], a2 = pW[2], a3 = pW[3];
            float dg = luW;
            float eR[RQ];
#pragma unroll
            for (int r = 0; r < RQ; ++r) {
                float t0 = dg + eW[r];
                float s01 = a0 + a1, s12 = a1 + a2, s23 = a2 + a3;  // off-chain
                float W0 = f[r*4+0] * (a0 + t0);
                float W1 = f[r*4+1] * (s01 + W0);
                float W2 = f[r*4+2] * (s12 + W1);
                float W3 = f[r*4+3] * (s23 + W2);
                eR[r] = W3;
                dg = eW[r];
                a0 = W0; a1 = W1; a2 = W2; a3 = W3;
            }

            // renorm by W33's exponent (integer scale, no transcendentals)
            const int e = ffrexpe(a3);
            const float sc = fldexp(1.0f, -e);

            if (active) {                  // masked commit
                pW[0] = a0 * sc; pW[1] = a1 * sc; pW[2] = a2 * sc; pW[3] = a3 * sc;
                luW = dg * sc;
                exW[0] = eR[0] * sc; exW[1] = eR[1] * sc;
                exW[2] = eR[2] * sc; exW[3] = eR[3] * sc;
                S += e; exS = S;
            }

            // producer: publish quad p (payload relaxed, flag release)
            if (isProd && active) {
                float* pp = payf + (size_t)(prodBase + p) * 5;
                __hip_atomic_store(pp + 0, exW[0], __ATOMIC_RELAXED, __HIP_MEMORY_SCOPE_AGENT);
                __hip_atomic_store(pp + 1, exW[1], __ATOMIC_RELAXED, __HIP_MEMORY_SCOPE_AGENT);
                __hip_atomic_store(pp + 2, exW[2], __ATOMIC_RELAXED, __HIP_MEMORY_SCOPE_AGENT);
                __hip_atomic_store(pp + 3, exW[3], __ATOMIC_RELAXED, __HIP_MEMORY_SCOPE_AGENT);
                __hip_atomic_store((int*)(pp + 4), exS, __ATOMIC_RELAXED, __HIP_MEMORY_SCOPE_AGENT);
                __hip_atomic_store(&flg[prodBase + p], p, __ATOMIC_RELEASE, __HIP_MEMORY_SCOPE_AGENT);
            }

            // issue D loads for iteration j+4 into the just-consumed slot
            {
                int pc = min(max(p + 4, 0), NQ - 1);
                const float* a = bp + (size_t)(pc * RQ) * N;
#pragma unroll
                for (int r = 0; r < RQ; ++r) gload4(ld[slot][r], a + (size_t)r * N);
            }

            // consumer: prefetch quad p+1's mailbox (one iteration early)
            if (isCons && (p + 1) < NQ) {
                const int sl = consBase + p + 1;
                while (__hip_atomic_load(&flg[sl], __ATOMIC_ACQUIRE, __HIP_MEMORY_SCOPE_AGENT) < p + 1) {}
                const float* pp = payf + (size_t)sl * 5;
                mpW[0] = __hip_atomic_load(pp + 0, __ATOMIC_RELAXED, __HIP_MEMORY_SCOPE_AGENT);
                mpW[1] = __hip_atomic_load(pp + 1, __ATOMIC_RELAXED, __HIP_MEMORY_SCOPE_AGENT);
                mpW[2] = __hip_atomic_load(pp + 2, __ATOMIC_RELAXED, __HIP_MEMORY_SCOPE_AGENT);
                mpW[3] = __hip_atomic_load(pp + 3, __ATOMIC_RELAXED, __HIP_MEMORY_SCOPE_AGENT);
                mpS    = __hip_atomic_load((const int*)(pp + 4), __ATOMIC_RELAXED, __HIP_MEMORY_SCOPE_AGENT);
            }

            // pipelined intra-wave handoff for NEXT iteration
            nW[0] = __shfl_up(exW[0], 1);
            nW[1] = __shfl_up(exW[1], 1);
            nW[2] = __shfl_up(exW[2], 1);
            nW[3] = __shfl_up(exW[3], 1);
            nS    = __shfl_up(exS, 1);
        }
    }

    // v2 = -(log2(W) + S); cost = v2 * ln2.  (panel 3, thread 63)
    if (q == NPAN - 1 && t == TPB - 1)
        out[b] = -(flog2(pW[KC - 1]) + (float)S) * LN2;
}

extern "C" void kernel_launch(void* const* d_in, const int* in_sizes, int n_in,
                              void* d_out, int out_size, void* d_ws, size_t ws_size,
                              hipStream_t stream) {
    const float* D = (const float*)d_in[0];
    float* out = (float*)d_out;
    const int B = in_sizes[0] / (N * N);

    const size_t flagBytes = (size_t)B * (NPAN - 1) * NQ * sizeof(int);
    int*   flg  = (int*)d_ws;
    float* payf = (float*)((char*)d_ws + flagBytes);

    // clear flags to -1 each launch (graph-capturable async memset)
    hipMemsetAsync(d_ws, 0xFF, flagBytes, stream);

    softdtw_kernel<<<B * NPAN, TPB, 0, stream>>>(D, out, flg, payf);
}

// Round 18
// 272.656 us; speedup vs baseline: 9.2477x; 9.2477x over previous
//
#include <hip/hip_runtime.h>

// Soft-DTW, gamma=1.0, B=64, N=M=1024. Linear-weight cells + integer-exponent
// scale tracking (R15/R16 numerics, proven absmax 0.0).
// R18: ONE WAVE PER BATCH (TPB=64, KC=16 columns/thread, 4 rows/iter).
// No mailbox, no LDS, no inter-wave coupling — every handoff is a pipelined
// __shfl_up within the wave. ITER = 256 + 63 = 319 (+1 pad). R17's cross-XCD
// global mailbox regressed 10x (poll on the critical path); R16's 2-wave LDS
// mailbox provably stalled the consumer ~1 iter per group. Single wave
// removes all of it.
// D: asm global_load_dwordx4 ring, depth 2 iterations (32 outstanding,
// 32KB in flight), counted s_waitcnt vmcnt(16), sched_barrier fence.

#define LOG2E 1.4426950408889634f
#define LN2  0.6931471805599453f

constexpr int N = 1024;
constexpr int TPB = 64;              // one wave
constexpr int KC = 16;               // columns per thread
constexpr int RQ = 4;                // rows per iteration (quad)
constexpr int NQ = N / RQ;           // 256 quads
constexpr int ITER = 320;            // last real iteration: 255 + 63 = 318

__device__ __forceinline__ float fexp2(float x){float r;asm("v_exp_f32 %0, %1":"=v"(r):"v"(x));return r;}
__device__ __forceinline__ float flog2(float x){float r;asm("v_log_f32 %0, %1":"=v"(r):"v"(x));return r;}
__device__ __forceinline__ int   ffrexpe(float x){int r;asm("v_frexp_exp_i32_f32 %0, %1":"=v"(r):"v"(x));return r;}
__device__ __forceinline__ float fldexp(float x, int e){float r;asm("v_ldexp_f32 %0, %1, %2":"=v"(r):"v"(x),"v"(e));return r;}
__device__ __forceinline__ void gload4(float4& d, const float* p){
    asm volatile("global_load_dwordx4 %0, %1, off" : "=v"(d) : "v"(p));
}

__global__ __launch_bounds__(TPB, 1)
void softdtw_kernel(const float* __restrict__ D, float* __restrict__ out){
    const int b = blockIdx.x;
    const int t = threadIdx.x;           // lane
    const float* __restrict__ bp = D + (size_t)b * N * N + t * KC;

    float pW[KC];                        // row-above weights (my scale)
#pragma unroll
    for (int k = 0; k < KC; ++k) pW[k] = 0.0f;
    int   S = 0;                          // scale: W_true = W * 2^S
    float luW = (t == 0) ? 1.0f : 0.0f;   // diagonal (DP[0][0]=1 for t0)
    float exW[RQ] = {0,0,0,0};            // exported right-edge W (col 15)
    int   exS = 0;
    float nW[RQ] = {0,0,0,0};             // shfl'd neighbor edges
    int   nS = 0;

    float4 ld[2][RQ][4];                 // [slot][row][16B-chunk]
#pragma unroll
    for (int x = 0; x < 2; ++x) {        // prologue: loads for j=0,1
        int pc = min(max(x - t, 0), NQ - 1);
        const float* a = bp + (size_t)(pc * RQ) * N;
#pragma unroll
        for (int r = 0; r < RQ; ++r)
#pragma unroll
            for (int h = 0; h < 4; ++h)
                gload4(ld[x][r][h], a + (size_t)r * N + 4 * h);
    }

    for (int jb = 0; jb < ITER; jb += 2) {
#pragma unroll
        for (int u = 0; u < 2; ++u) {
            const int j = jb + u;
            const int p = j - t;
            const bool active = (unsigned)p < (unsigned)NQ;
            const int slot = u;

            // incoming left edges (from shfl pipelined at end of prev iter)
            float i0 = nW[0], i1 = nW[1], i2 = nW[2], i3 = nW[3];
            int   iS = nS;
            if (t == 0) { i0 = i1 = i2 = i3 = 0.0f; iS = S; }

            // anchor my scale at my first quad
            if (p == 0) S = (t == 0) ? 0 : iS;

            // slot's 16 loads landed (issued 2 iterations ago)
            asm volatile("s_waitcnt vmcnt(16)" ::: "memory");
            __builtin_amdgcn_sched_barrier(0);

            // import edges into my scale (pure VALU)
            const int dS = iS - S;
            float eW[RQ];
            eW[0] = fldexp(i0, dS); eW[1] = fldexp(i1, dS);
            eW[2] = fldexp(i2, dS); eW[3] = fldexp(i3, dS);

            // ---- 64 cells: W = f*(up + diag + left), 16-wide rows ----
            float aW[KC];
#pragma unroll
            for (int k = 0; k < KC; ++k) aW[k] = pW[k];
            float dg = luW;
            float eR[RQ];
#pragma unroll
            for (int r = 0; r < RQ; ++r) {
                float f[KC];
#pragma unroll
                for (int h = 0; h < 4; ++h) {
                    const float4 dv = ld[slot][r][h];
                    f[h*4+0] = fexp2(-LOG2E * dv.x);
                    f[h*4+1] = fexp2(-LOG2E * dv.y);
                    f[h*4+2] = fexp2(-LOG2E * dv.z);
                    f[h*4+3] = fexp2(-LOG2E * dv.w);
                }
                float s[KC - 1];
#pragma unroll
                for (int k = 0; k < KC - 1; ++k) s[k] = aW[k] + aW[k + 1]; // off-chain
                float W = f[0] * (aW[0] + (dg + eW[r]));
                float Wn[KC];
                Wn[0] = W;
#pragma unroll
                for (int k = 1; k < KC; ++k) {
                    W = f[k] * (s[k - 1] + W);
                    Wn[k] = W;
                }
                eR[r] = W;
                dg = eW[r];
#pragma unroll
                for (int k = 0; k < KC; ++k) aW[k] = Wn[k];
            }

            // renorm by last cell's exponent (integer scale)
            const int e = ffrexpe(aW[KC - 1]);
            const float sc = fldexp(1.0f, -e);

            if (active) {                  // masked commit
#pragma unroll
                for (int k = 0; k < KC; ++k) pW[k] = aW[k] * sc;
                luW = dg * sc;
                exW[0] = eR[0] * sc; exW[1] = eR[1] * sc;
                exW[2] = eR[2] * sc; exW[3] = eR[3] * sc;
                S += e; exS = S;
            }

            // issue D loads for iteration j+2 into the just-consumed slot
            {
                int pc = min(max(p + 2, 0), NQ - 1);
                const float* a = bp + (size_t)(pc * RQ) * N;
#pragma unroll
                for (int r = 0; r < RQ; ++r)
#pragma unroll
                    for (int h = 0; h < 4; ++h)
                        gload4(ld[slot][r][h], a + (size_t)r * N + 4 * h);
            }

            // pipelined handoff for NEXT iteration
            nW[0] = __shfl_up(exW[0], 1);
            nW[1] = __shfl_up(exW[1], 1);
            nW[2] = __shfl_up(exW[2], 1);
            nW[3] = __shfl_up(exW[3], 1);
            nS    = __shfl_up(exS, 1);
        }
    }

    // v2 = -(log2(W) + S); cost = v2 * ln2.  (thread 63's last quad)
    if (t == TPB - 1) out[b] = -(flog2(pW[KC - 1]) + (float)S) * LN2;
}

extern "C" void kernel_launch(void* const* d_in, const int* in_sizes, int n_in,
                              void* d_out, int out_size, void* d_ws, size_t ws_size,
                              hipStream_t stream) {
    const float* D = (const float*)d_in[0];
    float* out = (float*)d_out;
    const int B = in_sizes[0] / (N * N);
    softdtw_kernel<<<B, TPB, 0, stream>>>(D, out);
}